// Round 23
// baseline (139.775 us; speedup 1.0000x reference)
//
#include <hip/hip_runtime.h>
#include <hip/hip_bf16.h>
#include <math.h>

// Problem constants: B=64, way=5, shot=1, D=640, H=W=5 (hw=25), nq=75, k=5
#define NB    64
#define WAY   5
#define DCH   640
#define HW    25
#define NQ    75
#define NBK   5
#define EPSN  1e-12f

#define QPB   4                          // queries per block = waves per block
#define BPB   ((NQ + QPB - 1) / QPB)     // 19 blocks per b
#define NWK   (NB * BPB)                 // 1216 work items
#define NDG   (DCH / 8)                  // 80 d-groups
#define SCOLS 128                        // 125 support cols + 3 zero pads
#define CD    32                         // chunk depth (d per staged chunk)
#define NCHK  (DCH / CD)                 // 20 chunks
#define CFL   (CD * HW)                  // 800 floats per chunk

typedef __attribute__((ext_vector_type(8)))  short  bf16x8;
typedef __attribute__((ext_vector_type(8)))  ushort u16x8;
typedef __attribute__((ext_vector_type(16))) float  f32x16;
typedef __attribute__((ext_vector_type(4)))  float  f32x4;

#define AS1 __attribute__((address_space(1)))
#define AS3 __attribute__((address_space(3)))

__device__ inline ushort f2bf(float f) {
    uint u = __float_as_uint(f);
    return (ushort)((u + 0x7FFFu + ((u >> 16) & 1u)) >> 16);   // RNE
}

// ---------------------------------------------------------------------------
// K1: per (b,way): invs, invsm, and MFMA-native bf16 A layout sT[dg][scol][8].
// ---------------------------------------------------------------------------
__global__ __launch_bounds__(256) void k_prep(const float* __restrict__ base,
                                              float* __restrict__ invs,
                                              float* __restrict__ invsm,
                                              ushort* __restrict__ sT)
{
    const int bk = blockIdx.x;                 // 0..319
    const int b  = bk / WAY;
    const int k  = bk - b * WAY;
    const float* src = base + (size_t)bk * (DCH * HW);
    __shared__ float lds[DCH * HW];
    __shared__ float red[256];
    const int tid = threadIdx.x;

    const f32x4* s4 = (const f32x4*)src;
    f32x4* l4 = (f32x4*)lds;
    for (int i = tid; i < (DCH * HW) / 4; i += 256)
        l4[i] = __builtin_nontemporal_load(s4 + i);
    __syncthreads();

    if (tid < HW) {
        float ss = 0.f;
        for (int d = 0; d < DCH; ++d) { float v = lds[d * HW + tid]; ss = fmaf(v, v, ss); }
        invs[bk * HW + tid] = rsqrtf(ss);      // ref: no eps on column norms
    }

    float ssq = 0.f;
    for (int d = tid; d < DCH; d += 256) {
        float s = 0.f;
        #pragma unroll
        for (int pp = 0; pp < HW; ++pp) s += lds[d * HW + pp];
        float m = s * (1.0f / HW);
        ssq = fmaf(m, m, ssq);
    }
    red[tid] = ssq;
    __syncthreads();
    for (int s = 128; s > 0; s >>= 1) {
        if (tid < s) red[tid] += red[tid + s];
        __syncthreads();
    }
    if (tid == 0) invsm[bk] = 1.0f / fmaxf(sqrtf(red[0]), EPSN);

    // transposed bf16 support write: [dg][scol][8]
    ushort* dstb = sT + (size_t)b * (NDG * SCOLS * 8);
    for (int t = tid; t < NDG * HW; t += 256) {
        const int dg = t / HW, l = t - dg * HW;
        u16x8 v;
        #pragma unroll
        for (int e = 0; e < 8; ++e) v[e] = f2bf(lds[(dg * 8 + e) * HW + l]);
        *(u16x8*)&dstb[((size_t)dg * SCOLS + k * HW + l) * 8] = v;
    }
    if (k == 0) {                              // zero pad scols 125..127
        const u16x8 z = (u16x8)(ushort)0;
        for (int t = tid; t < NDG * 3; t += 256) {
            const int dg = t / 3, sc = 125 + (t - dg * 3);
            *(u16x8*)&dstb[((size_t)dg * SCOLS + sc) * 8] = z;
        }
    }
}

// ---------------------------------------------------------------------------
// K2: SLIM-128 build, targeting 4 blocks/CU (16 waves/CU, 2 grid generations):
//  - no afA/afB banks (naked A loads; ~3us FIFO cost accepted, -64 VGPR)
//  - no accg Gram MFMA (-16 AGPR): ||qmean||^2 via fp32 LDS row-sums
//    (S_d = sum_p q[d][p], qsum += S_d^2; lanes 0-31, conflict-free);
//    ||q_p||^2 via scalar ssq on the B values (R6-validated numerics).
//  Budget: 64 AGPR + ~58 VGPR <= 128 -> __launch_bounds__(256,4).
// ---------------------------------------------------------------------------
__global__ __launch_bounds__(256, 4) void k_fused(const float* __restrict__ query,
                                                  const ushort* __restrict__ sT,
                                                  const float* __restrict__ invs,
                                                  const float* __restrict__ invsm,
                                                  const float* __restrict__ r,
                                                  float* __restrict__ out)
{
    __shared__ __align__(16) float lds_q[QPB][2][CFL];   // 25600 B, wave-private strips
    __shared__ float invs_l[SCOLS];
    __shared__ float invsm_l[WAY];

    const int tid  = threadIdx.x;
    const int wid  = tid >> 6;
    const int lane = tid & 63;
    const int p    = lane & 31;
    const int hi   = lane >> 5;

    // XCD-chunked swizzle: 1216 = 8 * 152, bijective.
    const int wk = (blockIdx.x & 7) * (int)(gridDim.x >> 3) + (blockIdx.x >> 3);
    const int b  = wk / BPB;
    const int qb = wk - b * BPB;
    const int q  = qb * QPB + wid;
    const bool qok = q < NQ;

    if (tid < WAY * HW) invs_l[tid] = invs[b * WAY * HW + tid];
    if (tid >= WAY * HW && tid < SCOLS) invs_l[tid] = 0.f;
    if (tid < WAY)      invsm_l[tid] = invsm[b * WAY + tid];
    __syncthreads();
    if (!qok) return;

    f32x16 acc0 = {}, acc1 = {}, acc2 = {}, acc3 = {};
    float ssq = 0.f;     // ||q_pc||^2 partial (this lane's hi-half of d)
    float qsum = 0.f;    // sum_d S_d^2 partial (lanes hi==0 only)

    const int pc = (p < HW) ? p : (HW - 1);     // clamp pad lanes
    const float* qrow = query + (size_t)(b * NQ + q) * (DCH * HW);
    const ushort* sTb = sT + (size_t)b * (NDG * SCOLS * 8);

    // B stage: chunk c -> lds_q[wid][c&1]: 3 full + 1 8-lane 16B/lane DMA (4 ops)
#define ISSUE(c)                                                               \
    {                                                                          \
        const float* src_ = qrow + (c) * CFL;                                  \
        float* dst_ = &lds_q[wid][(c) & 1][0];                                 \
        _Pragma("unroll")                                                      \
        for (int i = 0; i < 3; ++i)                                            \
            __builtin_amdgcn_global_load_lds(                                  \
                (const AS1 uint*)(src_ + i * 256 + lane * 4),                  \
                (AS3 uint*)(dst_ + i * 256), 16, 0, 0);                        \
        if (lane < 8)                                                          \
            __builtin_amdgcn_global_load_lds(                                  \
                (const AS1 uint*)(src_ + 768 + lane * 4),                      \
                (AS3 uint*)(dst_ + 768), 16, 0, 0);                            \
    }

    ISSUE(0)

    for (int c = 0; c < NCHK; ++c) {
        if (c + 1 < NCHK) {
            asm volatile("s_waitcnt lgkmcnt(0)" ::: "memory");
            ISSUE(c + 1)
            asm volatile("s_waitcnt vmcnt(4)" ::: "memory");   // chunk c landed
        } else {
            asm volatile("s_waitcnt vmcnt(0)" ::: "memory");
        }
        __builtin_amdgcn_sched_barrier(0);

        const float* strip = &lds_q[wid][c & 1][0];

        // ||qmean|| row-sums: lanes 0-31 each own row d = p of this chunk.
        if (hi == 0) {
            const float* row = strip + p * HW;
            float S = 0.f;
            #pragma unroll
            for (int j = 0; j < HW; ++j) S += row[j];
            qsum = fmaf(S, S, qsum);
        }

        __builtin_amdgcn_s_setprio(1);
        const float* qb_lds = strip + hi * 8 * HW + pc;
        #pragma unroll
        for (int ks = 0; ks < CD / 16; ++ks) {
            const int dg = c * (CD / 8) + ks * 2 + hi;
            const float v0 = qb_lds[(ks * 16 + 0) * HW];
            const float v1 = qb_lds[(ks * 16 + 1) * HW];
            const float v2 = qb_lds[(ks * 16 + 2) * HW];
            const float v3 = qb_lds[(ks * 16 + 3) * HW];
            const float v4 = qb_lds[(ks * 16 + 4) * HW];
            const float v5 = qb_lds[(ks * 16 + 5) * HW];
            const float v6 = qb_lds[(ks * 16 + 6) * HW];
            const float v7 = qb_lds[(ks * 16 + 7) * HW];
            ssq = fmaf(v0, v0, ssq); ssq = fmaf(v1, v1, ssq);
            ssq = fmaf(v2, v2, ssq); ssq = fmaf(v3, v3, ssq);
            ssq = fmaf(v4, v4, ssq); ssq = fmaf(v5, v5, ssq);
            ssq = fmaf(v6, v6, ssq); ssq = fmaf(v7, v7, ssq);
            union { uint u[4]; bf16x8 v; } bqu;
            asm("v_cvt_pk_bf16_f32 %0, %1, %2" : "=v"(bqu.u[0]) : "v"(v0), "v"(v1));
            asm("v_cvt_pk_bf16_f32 %0, %1, %2" : "=v"(bqu.u[1]) : "v"(v2), "v"(v3));
            asm("v_cvt_pk_bf16_f32 %0, %1, %2" : "=v"(bqu.u[2]) : "v"(v4), "v"(v5));
            asm("v_cvt_pk_bf16_f32 %0, %1, %2" : "=v"(bqu.u[3]) : "v"(v6), "v"(v7));
            const bf16x8 bq = bqu.v;
            const bf16x8* arow = (const bf16x8*)(sTb + (size_t)dg * SCOLS * 8);
            const bf16x8 a0 = arow[p];
            const bf16x8 a1 = arow[32 + p];
            const bf16x8 a2 = arow[64 + p];
            const bf16x8 a3 = arow[96 + p];
            acc0 = __builtin_amdgcn_mfma_f32_32x32x16_bf16(a0, bq, acc0, 0, 0, 0);
            acc1 = __builtin_amdgcn_mfma_f32_32x32x16_bf16(a1, bq, acc1, 0, 0, 0);
            acc2 = __builtin_amdgcn_mfma_f32_32x32x16_bf16(a2, bq, acc2, 0, 0, 0);
            acc3 = __builtin_amdgcn_mfma_f32_32x32x16_bf16(a3, bq, acc3, 0, 0, 0);
        }
        __builtin_amdgcn_s_setprio(0);
    }
#undef ISSUE

    // ---- epilogue (wave-local, shfl only) ----
    // C/D layout (m74/m101): col = lane&31, row = (reg&3) + 8*(reg>>2) + 4*hi.
    const bool pok = p < HW;

    // 1/||q_p||: both hi-halves hold disjoint d's (R6-validated)
    ssq += __shfl_xor(ssq, 32);
    const float invq = rsqrtf(ssq);

    // qq = sum_d S_d^2 = 625*||qmean||^2 (fp32-exact); lanes hi==1 hold 0
    float qq = qsum;

    // global-branch raw sums per way (RAW accs)
    float gs[WAY] = {0.f, 0.f, 0.f, 0.f, 0.f};
#define TILE_SUM(ACC, T)                                            \
    _Pragma("unroll")                                               \
    for (int rr = 0; rr < 16; ++rr) {                               \
        const int s0 = (T) * 32 + (rr & 3) + 8 * (rr >> 2);         \
        const float v0 = (hi || !pok) ? 0.f : ACC[rr];              \
        const float v1 = (hi && pok) ? ACC[rr] : 0.f;               \
        if (s0 < 125)     gs[s0 / 25]       += v0;                  \
        if (s0 + 4 < 125) gs[(s0 + 4) / 25] += v1;                  \
    }
    TILE_SUM(acc0, 0) TILE_SUM(acc1, 1) TILE_SUM(acc2, 2) TILE_SUM(acc3, 3)
#undef TILE_SUM

    #pragma unroll
    for (int o = 1; o < 64; o <<= 1) {
        qq += __shfl_xor(qq, o);
        #pragma unroll
        for (int g = 0; g < WAY; ++g) gs[g] += __shfl_xor(gs[g], o);
    }

    // in-place scale accs by column inv-norms (own-half scol = s0 + 4*hi)
#define SCALE(ACC, T)                                               \
    _Pragma("unroll")                                               \
    for (int rr = 0; rr < 16; ++rr) {                               \
        const int s0 = (T) * 32 + (rr & 3) + 8 * (rr >> 2);         \
        ACC[rr] *= invs_l[s0 + 4 * hi];                             \
    }
    SCALE(acc0, 0) SCALE(acc1, 1) SCALE(acc2, 2) SCALE(acc3, 3)
#undef SCALE

    // DN4: per way, gather the 25 sims (one shfl each), online top-5 insert
    float tots[WAY];
    #pragma unroll
    for (int g = 0; g < WAY; ++g) {
        float t0 = -3.402823466e38f, t1 = t0, t2 = t0, t3 = t0, t4 = t0;
        #pragma unroll
        for (int j = 0; j < HW; ++j) {
            const int scol = g * HW + j;
            const int t = scol >> 5, row = scol & 31;
            const int hreq = (row >> 2) & 1;
            const int rr = (row & 3) | ((row >> 3) << 2);
            const float av = (t == 0) ? acc0[rr] : (t == 1) ? acc1[rr]
                           : (t == 2) ? acc2[rr] : acc3[rr];
            float mine = (hi == hreq) ? av : 0.f;
            mine += __shfl_xor(mine, 32);
            float x = mine, a;
            a = fmaxf(t0, x); x = fminf(t0, x); t0 = a;
            a = fmaxf(t1, x); x = fminf(t1, x); t1 = a;
            a = fmaxf(t2, x); x = fminf(t2, x); t2 = a;
            a = fmaxf(t3, x); x = fminf(t3, x); t3 = a;
            a = fmaxf(t4, x); x = fminf(t4, x); t4 = a;
        }
        tots[g] = pok ? (t0 + t1 + t2 + t3 + t4) * invq : 0.f;
    }
    #pragma unroll
    for (int o = 1; o < 64; o <<= 1) {
        #pragma unroll
        for (int g = 0; g < WAY; ++g) tots[g] += __shfl_xor(tots[g], o);
    }

    const float r0 = r[0], r1 = r[1];
    const float invqm = 1.0f / fmaxf(sqrtf(qq) * (1.0f / HW), EPSN);  // 1/max(||qmean||,eps)
    float res[WAY];
    #pragma unroll
    for (int g = 0; g < WAY; ++g)
        res[g] = r0 * gs[g] * (1.0f / 625.0f) * invqm * invsm_l[g]
               + r1 * tots[g] * 0.5f * (1.0f / NBK);   // 0.5: hi-halves duplicate

    float ov = res[0];
    ov = (lane == 1) ? res[1] : ov;
    ov = (lane == 2) ? res[2] : ov;
    ov = (lane == 3) ? res[3] : ov;
    ov = (lane == 4) ? res[4] : ov;
    if (lane < WAY) out[(size_t)(b * NQ + q) * WAY + lane] = ov;
}

// ---------------------------------------------------------------------------
extern "C" void kernel_launch(void* const* d_in, const int* in_sizes, int n_in,
                              void* d_out, int out_size, void* d_ws, size_t ws_size,
                              hipStream_t stream)
{
    const float* base  = (const float*)d_in[0];
    const float* query = (const float*)d_in[1];
    const float* r     = (const float*)d_in[2];
    float* out = (float*)d_out;

    float* invs   = (float*)d_ws;                        // 320*25 floats
    float* invsm  = invs + NB * WAY * HW;                // 320 floats
    ushort* sT    = (ushort*)((float*)d_ws + 16384);     // 64 * 80*128*8 bf16 = 10 MB

    k_prep<<<NB * WAY, 256, 0, stream>>>(base, invs, invsm, sT);
    k_fused<<<NWK, 256, 0, stream>>>(query, sT, invs, invsm, r, out);
}

// Round 24
// 107.721 us; speedup vs baseline: 1.2976x; 1.2976x over previous
//
#include <hip/hip_runtime.h>
#include <hip/hip_bf16.h>
#include <math.h>

// Problem constants: B=64, way=5, shot=1, D=640, H=W=5 (hw=25), nq=75, k=5
#define NB    64
#define WAY   5
#define DCH   640
#define HW    25
#define NQ    75
#define NBK   5
#define EPSN  1e-12f

#define QPB   4                          // queries per block = waves per block
#define BPB   ((NQ + QPB - 1) / QPB)     // 19 blocks per b
#define NWK   (NB * BPB)                 // 1216 work items
#define NDG   (DCH / 8)                  // 80 d-groups
#define SCOLS 128                        // 125 support cols + 3 zero pads
#define CD    32                         // chunk depth (d per staged chunk)
#define NCHK  (DCH / CD)                 // 20 chunks
#define CFL   (CD * HW)                  // 800 floats per chunk

typedef __attribute__((ext_vector_type(8)))  short  bf16x8;
typedef __attribute__((ext_vector_type(8)))  ushort u16x8;
typedef __attribute__((ext_vector_type(16))) float  f32x16;
typedef __attribute__((ext_vector_type(4)))  float  f32x4;

#define AS1 __attribute__((address_space(1)))
#define AS3 __attribute__((address_space(3)))

__device__ inline ushort f2bf(float f) {
    uint u = __float_as_uint(f);
    return (ushort)((u + 0x7FFFu + ((u >> 16) & 1u)) >> 16);   // RNE
}

// ---------------------------------------------------------------------------
// K1: per (b,way): invs, invsm, and MFMA-native bf16 A layout sT[dg][scol][8].
// ---------------------------------------------------------------------------
__global__ __launch_bounds__(256) void k_prep(const float* __restrict__ base,
                                              float* __restrict__ invs,
                                              float* __restrict__ invsm,
                                              ushort* __restrict__ sT)
{
    const int bk = blockIdx.x;                 // 0..319
    const int b  = bk / WAY;
    const int k  = bk - b * WAY;
    const float* src = base + (size_t)bk * (DCH * HW);
    __shared__ float lds[DCH * HW];
    __shared__ float red[256];
    const int tid = threadIdx.x;

    const f32x4* s4 = (const f32x4*)src;
    f32x4* l4 = (f32x4*)lds;
    for (int i = tid; i < (DCH * HW) / 4; i += 256)
        l4[i] = __builtin_nontemporal_load(s4 + i);
    __syncthreads();

    if (tid < HW) {
        float ss = 0.f;
        for (int d = 0; d < DCH; ++d) { float v = lds[d * HW + tid]; ss = fmaf(v, v, ss); }
        invs[bk * HW + tid] = rsqrtf(ss);      // ref: no eps on column norms
    }

    float ssq = 0.f;
    for (int d = tid; d < DCH; d += 256) {
        float s = 0.f;
        #pragma unroll
        for (int pp = 0; pp < HW; ++pp) s += lds[d * HW + pp];
        float m = s * (1.0f / HW);
        ssq = fmaf(m, m, ssq);
    }
    red[tid] = ssq;
    __syncthreads();
    for (int s = 128; s > 0; s >>= 1) {
        if (tid < s) red[tid] += red[tid + s];
        __syncthreads();
    }
    if (tid == 0) invsm[bk] = 1.0f / fmaxf(sqrtf(red[0]), EPSN);

    // transposed bf16 support write: [dg][scol][8]
    ushort* dstb = sT + (size_t)b * (NDG * SCOLS * 8);
    for (int t = tid; t < NDG * HW; t += 256) {
        const int dg = t / HW, l = t - dg * HW;
        u16x8 v;
        #pragma unroll
        for (int e = 0; e < 8; ++e) v[e] = f2bf(lds[(dg * 8 + e) * HW + l]);
        *(u16x8*)&dstb[((size_t)dg * SCOLS + k * HW + l) * 8] = v;
    }
    if (k == 0) {                              // zero pad scols 125..127
        const u16x8 z = (u16x8)(ushort)0;
        for (int t = tid; t < NDG * 3; t += 256) {
            const int dg = t / 3, sc = 125 + (t - dg * 3);
            *(u16x8*)&dstb[((size_t)dg * SCOLS + sc) * 8] = z;
        }
    }
}

// ---------------------------------------------------------------------------
// K2: FINAL (R21, validated 108.3us). A-software-pipeline: CD=32, two A banks
// (afA/afB, 64 VGPR). Per iter exactly 12 VMEM ops (A8 + B4-DMA); vmcnt(12)
// retains the newest 12 (this iter's A(c+1)+B(c+1)) and drains the previous
// iter's 12 (A(c)+B(c)) regardless of intra-iteration scheduler interleave.
// A latency hides under compute(c-1); B prefetch stays in flight. Wave-private
// strips; no barriers in the loop; setprio(1) around the MFMA cluster.
// ---------------------------------------------------------------------------
__global__ __launch_bounds__(256, 2) void k_fused(const float* __restrict__ query,
                                                  const ushort* __restrict__ sT,
                                                  const float* __restrict__ invs,
                                                  const float* __restrict__ invsm,
                                                  const float* __restrict__ r,
                                                  float* __restrict__ out)
{
    __shared__ __align__(16) float lds_q[QPB][2][CFL];   // 25600 B, wave-private strips
    __shared__ float invs_l[SCOLS];
    __shared__ float invsm_l[WAY];

    const int tid  = threadIdx.x;
    const int wid  = tid >> 6;
    const int lane = tid & 63;
    const int p    = lane & 31;
    const int hi   = lane >> 5;

    // XCD-chunked swizzle: 1216 = 8 * 152, bijective.
    const int wk = (blockIdx.x & 7) * (int)(gridDim.x >> 3) + (blockIdx.x >> 3);
    const int b  = wk / BPB;
    const int qb = wk - b * BPB;
    const int q  = qb * QPB + wid;
    const bool qok = q < NQ;

    if (tid < WAY * HW) invs_l[tid] = invs[b * WAY * HW + tid];
    if (tid >= WAY * HW && tid < SCOLS) invs_l[tid] = 0.f;
    if (tid < WAY)      invsm_l[tid] = invsm[b * WAY + tid];
    __syncthreads();
    if (!qok) return;

    f32x16 acc0 = {}, acc1 = {}, acc2 = {}, acc3 = {}, accg = {};

    const int pc = (p < HW) ? p : (HW - 1);     // clamp pad lanes
    const float* qrow = query + (size_t)(b * NQ + q) * (DCH * HW);
    const ushort* sTb = sT + (size_t)b * (NDG * SCOLS * 8);

    // B stage: chunk c -> lds_q[wid][c&1]: 3 full + 1 8-lane 16B/lane DMA (4 ops)
#define ISSUE(c)                                                               \
    {                                                                          \
        const float* src_ = qrow + (c) * CFL;                                  \
        float* dst_ = &lds_q[wid][(c) & 1][0];                                 \
        _Pragma("unroll")                                                      \
        for (int i = 0; i < 3; ++i)                                            \
            __builtin_amdgcn_global_load_lds(                                  \
                (const AS1 uint*)(src_ + i * 256 + lane * 4),                  \
                (AS3 uint*)(dst_ + i * 256), 16, 0, 0);                        \
        if (lane < 8)                                                          \
            __builtin_amdgcn_global_load_lds(                                  \
                (const AS1 uint*)(src_ + 768 + lane * 4),                      \
                (AS3 uint*)(dst_ + 768), 16, 0, 0);                            \
    }

    // A stage: 8 fragments for chunk c -> static bank (8 loads)
#define LOAD_AF(BANK, c)                                                       \
    {                                                                          \
        _Pragma("unroll")                                                      \
        for (int ks = 0; ks < 2; ++ks) {                                       \
            const int dg = (c) * 4 + ks * 2 + hi;                              \
            const bf16x8* arow = (const bf16x8*)(sTb + (size_t)dg * SCOLS * 8);\
            BANK[ks * 4 + 0] = arow[p];                                        \
            BANK[ks * 4 + 1] = arow[32 + p];                                   \
            BANK[ks * 4 + 2] = arow[64 + p];                                   \
            BANK[ks * 4 + 3] = arow[96 + p];                                   \
        }                                                                      \
    }

#define COMPUTE(c, BANK)                                                       \
    {                                                                          \
        __builtin_amdgcn_s_setprio(1);                                         \
        const float* qb_lds = &lds_q[wid][(c) & 1][hi * 8 * HW + pc];          \
        _Pragma("unroll")                                                      \
        for (int ks = 0; ks < 2; ++ks) {                                       \
            const float v0 = qb_lds[(ks * 16 + 0) * HW];                       \
            const float v1 = qb_lds[(ks * 16 + 1) * HW];                       \
            const float v2 = qb_lds[(ks * 16 + 2) * HW];                       \
            const float v3 = qb_lds[(ks * 16 + 3) * HW];                       \
            const float v4 = qb_lds[(ks * 16 + 4) * HW];                       \
            const float v5 = qb_lds[(ks * 16 + 5) * HW];                       \
            const float v6 = qb_lds[(ks * 16 + 6) * HW];                       \
            const float v7 = qb_lds[(ks * 16 + 7) * HW];                       \
            union { uint u[4]; bf16x8 v; } bqu;                                \
            asm("v_cvt_pk_bf16_f32 %0, %1, %2" : "=v"(bqu.u[0]) : "v"(v0), "v"(v1)); \
            asm("v_cvt_pk_bf16_f32 %0, %1, %2" : "=v"(bqu.u[1]) : "v"(v2), "v"(v3)); \
            asm("v_cvt_pk_bf16_f32 %0, %1, %2" : "=v"(bqu.u[2]) : "v"(v4), "v"(v5)); \
            asm("v_cvt_pk_bf16_f32 %0, %1, %2" : "=v"(bqu.u[3]) : "v"(v6), "v"(v7)); \
            const bf16x8 bq = bqu.v;                                           \
            acc0 = __builtin_amdgcn_mfma_f32_32x32x16_bf16(BANK[ks * 4 + 0], bq, acc0, 0, 0, 0); \
            acc1 = __builtin_amdgcn_mfma_f32_32x32x16_bf16(BANK[ks * 4 + 1], bq, acc1, 0, 0, 0); \
            acc2 = __builtin_amdgcn_mfma_f32_32x32x16_bf16(BANK[ks * 4 + 2], bq, acc2, 0, 0, 0); \
            acc3 = __builtin_amdgcn_mfma_f32_32x32x16_bf16(BANK[ks * 4 + 3], bq, acc3, 0, 0, 0); \
            accg = __builtin_amdgcn_mfma_f32_32x32x16_bf16(bq, bq, accg, 0, 0, 0); \
        }                                                                      \
        __builtin_amdgcn_s_setprio(0);                                         \
    }

    // STEP: have A(c) in CUR (waited). Issue B(c+1)+A(c+1) (12 ops), then
    // vmcnt(12) drains the previous 12 (B(c)+A(c)) and keeps this iter's 12.
#define STEP(c, CUR, NXT)                                                      \
    {                                                                          \
        if ((c) + 1 < NCHK) {                                                  \
            asm volatile("s_waitcnt lgkmcnt(0)" ::: "memory");                 \
            ISSUE((c) + 1)                                                     \
            LOAD_AF(NXT, (c) + 1)                                              \
            asm volatile("s_waitcnt vmcnt(12)" ::: "memory");                  \
        } else {                                                               \
            asm volatile("s_waitcnt vmcnt(0)" ::: "memory");                   \
        }                                                                      \
        __builtin_amdgcn_sched_barrier(0);                                     \
        COMPUTE(c, CUR)                                                        \
    }

    bf16x8 afA[8], afB[8];
    ISSUE(0)
    LOAD_AF(afA, 0)          // prologue: 12 ops outstanding (B(0)+A(0))

    #pragma unroll 1
    for (int c = 0; c < NCHK; c += 2) {
        STEP(c,     afA, afB)
        STEP(c + 1, afB, afA)
    }
#undef ISSUE
#undef LOAD_AF
#undef COMPUTE
#undef STEP

    // ---- epilogue (wave-local, shfl only; R14-validated numerics) ----
    // C/D layout (m74/m101): col = lane&31, row = (reg&3) + 8*(reg>>2) + 4*hi.
    const bool pok = p < HW;

    // 1/||q_p|| from Gram diagonal + Gram total for ||qmean||
    float diag = 0.f, qq = 0.f;
    #pragma unroll
    for (int rr = 0; rr < 16; ++rr) {
        const int rowb = (rr & 3) + 8 * (rr >> 2);
        const int row  = rowb + 4 * hi;
        diag = (row == p) ? accg[rr] : diag;
        if (row < HW && pok) qq += accg[rr];
    }
    diag += __shfl_xor(diag, 32);
    const float invq = rsqrtf(diag);

    // global-branch raw sums per way (RAW accs)
    float gs[WAY] = {0.f, 0.f, 0.f, 0.f, 0.f};
#define TILE_SUM(ACC, T)                                            \
    _Pragma("unroll")                                               \
    for (int rr = 0; rr < 16; ++rr) {                               \
        const int s0 = (T) * 32 + (rr & 3) + 8 * (rr >> 2);         \
        const float v0 = (hi || !pok) ? 0.f : ACC[rr];              \
        const float v1 = (hi && pok) ? ACC[rr] : 0.f;               \
        if (s0 < 125)     gs[s0 / 25]       += v0;                  \
        if (s0 + 4 < 125) gs[(s0 + 4) / 25] += v1;                  \
    }
    TILE_SUM(acc0, 0) TILE_SUM(acc1, 1) TILE_SUM(acc2, 2) TILE_SUM(acc3, 3)
#undef TILE_SUM

    #pragma unroll
    for (int o = 1; o < 64; o <<= 1) {
        qq += __shfl_xor(qq, o);
        #pragma unroll
        for (int g = 0; g < WAY; ++g) gs[g] += __shfl_xor(gs[g], o);
    }

    // in-place scale accs by column inv-norms (own-half scol = s0 + 4*hi)
#define SCALE(ACC, T)                                               \
    _Pragma("unroll")                                               \
    for (int rr = 0; rr < 16; ++rr) {                               \
        const int s0 = (T) * 32 + (rr & 3) + 8 * (rr >> 2);         \
        ACC[rr] *= invs_l[s0 + 4 * hi];                             \
    }
    SCALE(acc0, 0) SCALE(acc1, 1) SCALE(acc2, 2) SCALE(acc3, 3)
#undef SCALE

    // DN4: per way, gather the 25 sims (one shfl each), online top-5 insert
    float tots[WAY];
    #pragma unroll
    for (int g = 0; g < WAY; ++g) {
        float t0 = -3.402823466e38f, t1 = t0, t2 = t0, t3 = t0, t4 = t0;
        #pragma unroll
        for (int j = 0; j < HW; ++j) {
            const int scol = g * HW + j;
            const int t = scol >> 5, row = scol & 31;
            const int hreq = (row >> 2) & 1;
            const int rr = (row & 3) | ((row >> 3) << 2);
            const float av = (t == 0) ? acc0[rr] : (t == 1) ? acc1[rr]
                           : (t == 2) ? acc2[rr] : acc3[rr];
            float mine = (hi == hreq) ? av : 0.f;
            mine += __shfl_xor(mine, 32);
            float x = mine, a;
            a = fmaxf(t0, x); x = fminf(t0, x); t0 = a;
            a = fmaxf(t1, x); x = fminf(t1, x); t1 = a;
            a = fmaxf(t2, x); x = fminf(t2, x); t2 = a;
            a = fmaxf(t3, x); x = fminf(t3, x); t3 = a;
            a = fmaxf(t4, x); x = fminf(t4, x); t4 = a;
        }
        tots[g] = pok ? (t0 + t1 + t2 + t3 + t4) * invq : 0.f;
    }
    #pragma unroll
    for (int o = 1; o < 64; o <<= 1) {
        #pragma unroll
        for (int g = 0; g < WAY; ++g) tots[g] += __shfl_xor(tots[g], o);
    }

    const float r0 = r[0], r1 = r[1];
    const float invqm = 1.0f / fmaxf(sqrtf(qq) * (1.0f / HW), EPSN);  // 1/max(||qmean||,eps)
    float res[WAY];
    #pragma unroll
    for (int g = 0; g < WAY; ++g)
        res[g] = r0 * gs[g] * (1.0f / 625.0f) * invqm * invsm_l[g]
               + r1 * tots[g] * 0.5f * (1.0f / NBK);   // 0.5: hi-halves duplicate

    float ov = res[0];
    ov = (lane == 1) ? res[1] : ov;
    ov = (lane == 2) ? res[2] : ov;
    ov = (lane == 3) ? res[3] : ov;
    ov = (lane == 4) ? res[4] : ov;
    if (lane < WAY) out[(size_t)(b * NQ + q) * WAY + lane] = ov;
}

// ---------------------------------------------------------------------------
extern "C" void kernel_launch(void* const* d_in, const int* in_sizes, int n_in,
                              void* d_out, int out_size, void* d_ws, size_t ws_size,
                              hipStream_t stream)
{
    const float* base  = (const float*)d_in[0];
    const float* query = (const float*)d_in[1];
    const float* r     = (const float*)d_in[2];
    float* out = (float*)d_out;

    float* invs   = (float*)d_ws;                        // 320*25 floats
    float* invsm  = invs + NB * WAY * HW;                // 320 floats
    ushort* sT    = (ushort*)((float*)d_ws + 16384);     // 64 * 80*128*8 bf16 = 10 MB

    k_prep<<<NB * WAY, 256, 0, stream>>>(base, invs, invsm, sT);
    k_fused<<<NWK, 256, 0, stream>>>(query, sT, invs, invsm, r, out);
}